// Round 6
// baseline (213.553 us; speedup 1.0000x reference)
//
#include <hip/hip_runtime.h>

// Problem geometry (fixed by the reference): B=8, H=1024, W=1024, periodic.
#define WMASK 1023
#define LOG2W 10
#define HW (1024 * 1024)

#define EPS 1e-6f
#define DT 1e-2f

// Output tile 64x16 per block (256 threads), all phases vectorized 4-wide.
// Raw LDS rows: 80 floats, valid cols 4..75  <-> gx = x0-4 .. x0+67 (col = gx-x0+8)
// dF  LDS rows: 80 floats, valid cols 7..72  <-> x  = x0-1 .. x0+64
#define TX 64
#define TY 16
#define RXP 80
#define RYH 20         // raw rows: y0-2 .. y0+17
#define DYH 18         // dF rows:  y0-1 .. y0+16

typedef float f4 __attribute__((ext_vector_type(4)));   // native vector: OK for nontemporal builtins

__device__ __forceinline__ float scal(const float* __restrict__ p) {
    return fabsf(p[0]) + 0.001f;
}
__device__ __forceinline__ float logm(float m) {
    // jnp.log(jnp.where(m < eps, eps, m)); hw log err ~1e-5 abs, threshold 2e-2
    return __logf(m < EPS ? EPS : m);
}
__device__ __forceinline__ float clip01(float v) {
    return fminf(fmaxf(v, 0.0f), 1.0f);
}

__global__ __launch_bounds__(256) void irr_fused(
    const float* __restrict__ cv,
    const float* __restrict__ ci,
    const float* __restrict__ eta,
    const float* __restrict__ p_ev,
    const float* __restrict__ p_ei,
    const float* __restrict__ p_kbt,
    const float* __restrict__ p_kv,
    const float* __restrict__ p_ki,
    const float* __restrict__ p_ke,
    const float* __restrict__ p_dv,
    const float* __restrict__ p_di,
    const float* __restrict__ p_L,
    float* __restrict__ cv_new,
    float* __restrict__ ci_new,
    float* __restrict__ eta_new)
{
    __shared__ float scv[RYH][RXP];
    __shared__ float sci[RYH][RXP];
    __shared__ float seta[RYH][RXP];
    __shared__ float sdv[DYH][RXP];
    __shared__ float sdi[DYH][RXP];

    const int tid = threadIdx.x;
    const int x0 = blockIdx.x * TX;
    const int y0 = blockIdx.y * TY;
    const int bbase = blockIdx.z * HW;

    const float energy_v = scal(p_ev);
    const float energy_i = scal(p_ei);
    const float kBT      = scal(p_kbt);
    const float kappa_v  = scal(p_kv);
    const float kappa_i  = scal(p_ki);
    const float kappa_e  = scal(p_ke);
    const float L        = scal(p_L);
    const float rv = scal(p_dv) / kBT;   // mv = rv * c0
    const float ri = scal(p_di) / kBT;

    // ---- Stage raw fields: 3 fields x 20 rows x 18 f4-chunks = 1080 ----
    for (int t = tid; t < 1080; t += 256) {
        const int f  = t / 360;
        const int r  = t - f * 360;
        const int cy = r / 18;
        const int c  = r - cy * 18 + 1;          // chunk 1..18 -> col 4c
        const int gx = (x0 + 4 * c - 8) & WMASK; // 4-aligned, no row-cross
        const int gy = (y0 - 2 + cy) & WMASK;
        const float* __restrict__ src = (f == 0) ? cv : (f == 1) ? ci : eta;
        const f4 v = *(const f4*)(src + bbase + (gy << LOG2W) + gx);
        float* dst = (f == 0) ? &scv[cy][4 * c]
                   : (f == 1) ? &sci[cy][4 * c]
                              : &seta[cy][4 * c];
        *(f4*)dst = v;
    }
    __syncthreads();

    // ---- Phase 1: dF on 18 rows x 18 chunks = 324 f4 groups ----
    for (int t = tid; t < 324; t += 256) {
        const int row = t / 18;            // ey 0..17 ; gy = y0 + row - 1
        const int c   = t - row * 18 + 1;  // 1..18
        const int col = 4 * c;
        const int ry  = row + 1;           // raw row

        const f4 cM4 = *(const f4*)&scv[ry][col];
        const float cL = scv[ry][col - 1];
        const float cR = scv[ry][col + 4];
        const f4 cU4 = *(const f4*)&scv[ry - 1][col];
        const f4 cD4 = *(const f4*)&scv[ry + 1][col];

        const f4 iM4 = *(const f4*)&sci[ry][col];
        const float iL = sci[ry][col - 1];
        const float iR = sci[ry][col + 4];
        const f4 iU4 = *(const f4*)&sci[ry - 1][col];
        const f4 iD4 = *(const f4*)&sci[ry + 1][col];

        const f4 eM4 = *(const f4*)&seta[ry][col];
        const float eL = seta[ry][col - 1];
        const float eR = seta[ry][col + 4];
        const f4 eU4 = *(const f4*)&seta[ry - 1][col];
        const f4 eD4 = *(const f4*)&seta[ry + 1][col];

        f4 dv4, di4, et4;

#pragma unroll
        for (int j = 0; j < 4; ++j) {
            const float c0 = cM4[j];
            const float i0 = iM4[j];
            const float e0 = eM4[j];
            const float cxl = (j == 0) ? cL : cM4[j - 1];
            const float cxr = (j == 3) ? cR : cM4[j + 1];
            const float ixl = (j == 0) ? iL : iM4[j - 1];
            const float ixr = (j == 3) ? iR : iM4[j + 1];
            const float exl = (j == 0) ? eL : eM4[j - 1];
            const float exr = (j == 3) ? eR : eM4[j + 1];

            const float lap_cv  = cxl + cxr + cU4[j] + cD4[j] - 4.0f * c0;
            const float lap_ci  = ixl + ixr + iU4[j] + iD4[j] - 4.0f * i0;
            const float lap_eta = exl + exr + eU4[j] + eD4[j] - 4.0f * e0;

            const float h  = (e0 - 1.0f) * (e0 - 1.0f);
            const float jj = e0 * e0;
            const float cs = 1.0f - c0 - i0;
            const float lcv = logm(c0);
            const float lci = logm(i0);
            const float lcs = logm(cs);

            const float fs = energy_v * c0 + energy_i * i0
                           + kBT * (c0 * lcv + i0 * lci + cs * lcs);
            const float dfs_dcv = energy_v + kBT * (lcv - lcs);
            const float dfs_dci = energy_i + kBT * (lci - lcs);
            const float fv = (c0 - 1.0f) * (c0 - 1.0f) + i0 * i0;

            dv4[j] = h * dfs_dcv + jj * (2.0f * (c0 - 1.0f)) - kappa_v * lap_cv;
            di4[j] = h * dfs_dci + jj * (2.0f * i0)          - kappa_i * lap_ci;
            const float dF_deta = fs * 2.0f * (e0 - 1.0f) + fv * 2.0f * e0
                                - kappa_e * lap_eta;   // N_PARAM == 1.0
            et4[j] = clip01(e0 + DT * (-L * dF_deta));
        }

        *(f4*)&sdv[row][col] = dv4;
        *(f4*)&sdi[row][col] = di4;

        // eta_new: interior cols 8..71 (c in [2,17]) and rows 1..16
        if (c >= 2 && c <= 17 && row >= 1 && row <= 16) {
            const int gidx = bbase + ((y0 + row - 1) << LOG2W) + (x0 + col - 8);
            __builtin_nontemporal_store(et4, (f4*)&eta_new[gidx]);
        }
    }
    __syncthreads();

    // ---- Phase 2: exactly one f4 group per thread (16 rows x 16 chunks) ----
    {
        const int oy  = tid >> 4;          // 0..15
        const int cg  = tid & 15;          // 0..15
        const int col = 8 + 4 * cg;        // dF col of first output
        const int ey  = oy + 1;

        const f4 vM4 = *(const f4*)&sdv[ey][col];
        const float vL = sdv[ey][col - 1];
        const float vR = sdv[ey][col + 4];
        const f4 vU4 = *(const f4*)&sdv[ey - 1][col];
        const f4 vD4 = *(const f4*)&sdv[ey + 1][col];

        const f4 wM4 = *(const f4*)&sdi[ey][col];
        const float wL = sdi[ey][col - 1];
        const float wR = sdi[ey][col + 4];
        const f4 wU4 = *(const f4*)&sdi[ey - 1][col];
        const f4 wD4 = *(const f4*)&sdi[ey + 1][col];

        const f4 c4 = *(const f4*)&scv[oy + 2][col];
        const f4 i4 = *(const f4*)&sci[oy + 2][col];

        f4 cvo, cio;

#pragma unroll
        for (int j = 0; j < 4; ++j) {
            const float v0 = vM4[j];
            const float w0 = wM4[j];
            const float vxl = (j == 0) ? vL : vM4[j - 1];
            const float vxr = (j == 3) ? vR : vM4[j + 1];
            const float wxl = (j == 0) ? wL : wM4[j - 1];
            const float wxr = (j == 3) ? wR : wM4[j + 1];

            const float lap_v = vxl + vxr + vU4[j] + vD4[j] - 4.0f * v0;
            const float lap_w = wxl + wxr + wU4[j] + wD4[j] - 4.0f * w0;

            cvo[j] = clip01(c4[j] + DT * ((rv * c4[j]) * lap_v));
            cio[j] = clip01(i4[j] + DT * ((ri * i4[j]) * lap_w));
        }

        const int gidx = bbase + ((y0 + oy) << LOG2W) + (x0 + 4 * cg);
        __builtin_nontemporal_store(cvo, (f4*)&cv_new[gidx]);
        __builtin_nontemporal_store(cio, (f4*)&ci_new[gidx]);
    }
}

extern "C" void kernel_launch(void* const* d_in, const int* in_sizes, int n_in,
                              void* d_out, int out_size, void* d_ws, size_t ws_size,
                              hipStream_t stream) {
    // Input order: cv, ci, eta, energy_v0, energy_i0, kBT0, kappa_v0, kappa_i0,
    //              kappa_eta0, diff_v0, diff_i0, L0  — all float32 per reference.
    const float* cv  = (const float*)d_in[0];
    const float* ci  = (const float*)d_in[1];
    const float* eta = (const float*)d_in[2];
    const float* p_ev  = (const float*)d_in[3];
    const float* p_ei  = (const float*)d_in[4];
    const float* p_kbt = (const float*)d_in[5];
    const float* p_kv  = (const float*)d_in[6];
    const float* p_ki  = (const float*)d_in[7];
    const float* p_ke  = (const float*)d_in[8];
    const float* p_dv  = (const float*)d_in[9];
    const float* p_di  = (const float*)d_in[10];
    const float* p_L   = (const float*)d_in[11];

    const int N = in_sizes[0];  // 8*1024*1024

    float* out     = (float*)d_out;
    float* cv_new  = out;
    float* ci_new  = out + N;
    float* eta_new = out + 2 * N;

    const dim3 block(256);
    const dim3 grid(1024 / TX, 1024 / TY, N / HW);  // (16, 64, 8)

    irr_fused<<<grid, block, 0, stream>>>(cv, ci, eta, p_ev, p_ei, p_kbt,
                                          p_kv, p_ki, p_ke, p_dv, p_di, p_L,
                                          cv_new, ci_new, eta_new);
}